// Round 18
// baseline (537.349 us; speedup 1.0000x reference)
//
#include <hip/hip_runtime.h>

// MaxChamferDistance: x[16,4096,3], y[16,4096,3] f32 -> scalar f32
//
// Round-18: cross-round invariant isolated: ~112 cy/MFMA per SIMD across all
// schedules (vs 32 cy issue) -- the min-tree reads each MFMA's acc
// immediately, forcing a full matrix-pipe drain per tile (the 2495TF ubench
// chains acc INSIDE the pipe; we never did). r17 double-buffered the A-read
// but not the ACC CONSUMPTION. Fix: software-pipeline the accumulator --
// issue tile mt+1's MFMAs into fresh acc regs BEFORE min-reading tile mt's.
// 2-deep, named vars (no runtime indexing), unroll 2 => free rotation.
// +32 VGPR (~110 total < 128 cap). Everything else r12-verbatim
// (champion 29.8us, absmax 0 x7).

typedef __attribute__((ext_vector_type(8)))  short bf16x8;
typedef __attribute__((ext_vector_type(16))) float f32x16;

#define BATCH   16
#define NPTS    4096
#define DB      (2 * BATCH)            // 32 (dir,batch)
#define GM_F32  (2 * DB * NPTS)        // 262144 f32 = 1 MB

static __device__ __forceinline__ unsigned bf16rn(float f) {
  unsigned u = __float_as_uint(f);
  return (u + 0x7FFFu + ((u >> 16) & 1u)) >> 16;   // round-to-nearest-even
}
static __device__ __forceinline__ float bf2f(unsigned h) {
  return __uint_as_float(h << 16);
}
static __device__ __forceinline__ unsigned pk(unsigned lo, unsigned hi) {
  return (lo & 0xFFFFu) | (hi << 16);
}

static __device__ __forceinline__ float mintree16(const f32x16& a) {
  float m0 = fminf(fminf(a[0],  a[1]),  a[2]);     // v_min3 chains
  float m1 = fminf(fminf(a[3],  a[4]),  a[5]);
  float m2 = fminf(fminf(a[6],  a[7]),  a[8]);
  float m3 = fminf(fminf(a[9],  a[10]), a[11]);
  float m4 = fminf(fminf(a[12], a[13]), a[14]);
  float m5 = fminf(fminf(a[15], m0), m1);
  float m6 = fminf(fminf(m2, m3), m4);
  return fminf(m5, m6);
}

__global__ __launch_bounds__(512, 4) void chamfer_mm(
    const float* __restrict__ x, const float* __restrict__ y,
    float* __restrict__ gm, unsigned* __restrict__ cnt) {
  // 64 m-tiles x 64 uint4 (tile layout: [kh(2)][row(32)]) = 64 KB
  __shared__ __align__(16) uint4 afl[64 * 64];

  const int bid = blockIdx.x;          // 512 = 32 db x 8 own-chunks x 2 halves
  const int tid = threadIdx.x;
  if (bid == 0 && tid == 0) *cnt = 0;  // combine's counter (stream-ordered)

  const int db  = bid >> 4;
  const int r   = bid & 15;
  const int c   = r >> 1;              // own chunk [0,8)
  const int h   = r & 1;               // m-half
  const int dir = db >> 4, b = db & 15;
  const float* own   = (dir == 0 ? x : y) + (size_t)b * NPTS * 3;
  const float* other = (dir == 0 ? y : x) + (size_t)b * NPTS * 3;
  const float* mp    = other + (size_t)h * 2048 * 3;

  // ---- stage: convert 2048 other pts -> A-frags in LDS (4 pts/thread) ----
  #pragma unroll
  for (int k = 0; k < 4; ++k) {
    const int p = tid + k * 512;       // [0,2048)
    float y0 = mp[p * 3 + 0], y1 = mp[p * 3 + 1], y2 = mp[p * 3 + 2];
    float wv = fmaf(y2, y2, fmaf(y1, y1, y0 * y0));
    float z0 = -2.f * y0, z1 = -2.f * y1, z2 = -2.f * y2;
    unsigned h0 = bf16rn(z0), h1 = bf16rn(z1), h2 = bf16rn(z2);
    unsigned e0 = bf16rn(z0 - bf2f(h0));
    unsigned e1 = bf16rn(z1 - bf2f(h1));
    unsigned e2 = bf16rn(z2 - bf2f(h2));
    unsigned wh = bf16rn(wv), wl = bf16rn(wv - bf2f(wh));
    const int tile = p >> 5, row = p & 31;
    afl[tile * 64 + row]      =
        make_uint4(pk(h0, h1), pk(h2, e0), pk(e1, e2), pk(h0, h1)); // K0-7
    afl[tile * 64 + 32 + row] =
        make_uint4(pk(h2, wh), pk(wl, 0u), 0u, 0u);                 // K8-15
  }

  // ---- resident B-frags: 64 own pts per wave (2 n-tiles of 32) ----------
  const int w = tid >> 6, l = tid & 63;
  const int col = l & 31, kh = l >> 5;
  const unsigned ONE = 0x3F80u;
  bf16x8 bfr[2];
  float sq[2], rmn[2];
  #pragma unroll
  for (int nt = 0; nt < 2; ++nt) {
    const int n = c * 512 + w * 64 + nt * 32 + col;
    float a0 = own[n * 3 + 0], a1 = own[n * 3 + 1], a2 = own[n * 3 + 2];
    sq[nt]  = fmaf(a2, a2, fmaf(a1, a1, a0 * a0));   // exact f32, added last
    rmn[nt] = 1e30f;
    unsigned h0 = bf16rn(a0), h1 = bf16rn(a1), h2 = bf16rn(a2);
    unsigned e0 = bf16rn(a0 - bf2f(h0));
    unsigned e1 = bf16rn(a1 - bf2f(h1));
    unsigned e2 = bf16rn(a2 - bf2f(h2));
    union { unsigned uu[4]; bf16x8 v; } U;
    U.uu[0] = (kh == 0) ? pk(h0, h1) : pk(e2, ONE);
    U.uu[1] = (kh == 0) ? pk(h2, h0) : pk(ONE, 0u);
    U.uu[2] = (kh == 0) ? pk(h1, h2) : 0u;
    U.uu[3] = (kh == 0) ? pk(e0, e1) : 0u;
    bfr[nt] = U.v;
  }
  __syncthreads();

  // ---- main loop: ACC-pipelined (issue mt+1 before reading mt) ----------
  const int aoff = kh * 32 + col;      // lane's uint4 index within a tile
  const f32x16 z16 = {0.f, 0.f, 0.f, 0.f, 0.f, 0.f, 0.f, 0.f,
                      0.f, 0.f, 0.f, 0.f, 0.f, 0.f, 0.f, 0.f};
  union { uint4 u; bf16x8 v; } A;
  A.u = afl[aoff];                     // tile 0
  f32x16 accP0 = __builtin_amdgcn_mfma_f32_32x32x16_bf16(A.v, bfr[0], z16,
                                                         0, 0, 0);
  f32x16 accP1 = __builtin_amdgcn_mfma_f32_32x32x16_bf16(A.v, bfr[1], z16,
                                                         0, 0, 0);
  #pragma unroll 2
  for (int mt = 1; mt < 64; ++mt) {
    A.u = afl[mt * 64 + aoff];
    // issue next tile's MFMAs first: they drain while we read the previous
    f32x16 accC0 = __builtin_amdgcn_mfma_f32_32x32x16_bf16(A.v, bfr[0], z16,
                                                           0, 0, 0);
    f32x16 accC1 = __builtin_amdgcn_mfma_f32_32x32x16_bf16(A.v, bfr[1], z16,
                                                           0, 0, 0);
    rmn[0] = fminf(rmn[0], mintree16(accP0));        // reads tile mt-1
    rmn[1] = fminf(rmn[1], mintree16(accP1));
    accP0 = accC0;                                   // rotation (unroll 2)
    accP1 = accC1;
  }
  rmn[0] = fminf(rmn[0], mintree16(accP0));          // drain tile 63
  rmn[1] = fminf(rmn[1], mintree16(accP1));

  // ---- epilogue: rows live in both lane halves -> fold lane^32 ----------
  #pragma unroll
  for (int nt = 0; nt < 2; ++nt) {
    float v = fminf(rmn[nt], __shfl_xor(rmn[nt], 32, 64));
    float sv = v + sq[nt];
    if (l < 32)
      gm[(size_t)(h * DB + db) * NPTS + c * 512 + w * 64 + nt * 32 + col] = sv;
  }
}

// 32 blocks: min over halves + per-db mean; last block folds max/mean -> out.
__global__ __launch_bounds__(256) void chamfer_combine(
    const float* __restrict__ gm, float* __restrict__ dist,
    unsigned* __restrict__ cnt, float* __restrict__ out) {
  const int db = blockIdx.x;
  const float* g0 = gm + (size_t)db * NPTS;
  const float* g1 = gm + (size_t)(DB + db) * NPTS;
  float s = 0.0f;
  for (int i = threadIdx.x; i < NPTS; i += 256)
    s += fminf(g0[i], g1[i]);
  #pragma unroll
  for (int off = 32; off > 0; off >>= 1) s += __shfl_down(s, off, 64);
  __shared__ float red[4];
  const int lane = threadIdx.x & 63, wid = threadIdx.x >> 6;
  if (lane == 0) red[wid] = s;
  __syncthreads();
  if (threadIdx.x == 0) {
    dist[db] = ((red[0] + red[1]) + (red[2] + red[3])) * (1.0f / (float)NPTS);
    __threadfence();
    unsigned old = __hip_atomic_fetch_add(cnt, 1u, __ATOMIC_ACQ_REL,
                                          __HIP_MEMORY_SCOPE_AGENT);
    if (old == DB - 1) {
      __threadfence();
      float acc = 0.0f;
      #pragma unroll
      for (int b = 0; b < BATCH; ++b) {
        float d0 = __uint_as_float(__hip_atomic_load(
            (const unsigned*)&dist[b], __ATOMIC_RELAXED,
            __HIP_MEMORY_SCOPE_AGENT));
        float d1 = __uint_as_float(__hip_atomic_load(
            (const unsigned*)&dist[b + BATCH], __ATOMIC_RELAXED,
            __HIP_MEMORY_SCOPE_AGENT));
        acc += fmaxf(d0, d1);
      }
      out[0] = acc * (1.0f / (float)BATCH);
    }
  }
}

extern "C" void kernel_launch(void* const* d_in, const int* in_sizes, int n_in,
                              void* d_out, int out_size, void* d_ws, size_t ws_size,
                              hipStream_t stream) {
  const float* x = (const float*)d_in[0];
  const float* y = (const float*)d_in[1];
  float* out = (float*)d_out;

  float* gm     = (float*)d_ws;                    // 1 MB
  float* dist   = gm + GM_F32;                     // 32 f32
  unsigned* cnt = (unsigned*)(dist + DB);          // 1 u32

  chamfer_mm<<<512, 512, 0, stream>>>(x, y, gm, cnt);
  chamfer_combine<<<DB, 256, 0, stream>>>(gm, dist, cnt, out);
}

// Round 19
// 432.871 us; speedup vs baseline: 1.2414x; 1.2414x over previous
//
#include <hip/hip_runtime.h>

// MaxChamferDistance: x[16,4096,3], y[16,4096,3] f32 -> scalar f32
//
// Round-19: r18's acc-pipeline test was CORRUPTED by VGPR spill (the
// launch_bounds(512,4)=128-VGPR cap couldn't hold 2 extra f32x16 accs ->
// 1.85GB scratch traffic, 537us). Re-run the identical experiment with
// launch_bounds(512,2): VGPR budget 256, no spill. Occupancy is LDS-bound
// anyway (64KB -> 2 blocks/CU = 4 waves/SIMD, same as r12), and 2-6
// waves/SIMD were proven equivalent (r12/r14). Everything else r18-verbatim:
// issue tile mt+1's MFMAs into fresh accs BEFORE min-reading tile mt's accs
// (tests whether acc-read-after-MFMA pipe drain is the 112cy/MFMA wall).
// Numerics/combine r12-verbatim (absmax 0 x8).

typedef __attribute__((ext_vector_type(8)))  short bf16x8;
typedef __attribute__((ext_vector_type(16))) float f32x16;

#define BATCH   16
#define NPTS    4096
#define DB      (2 * BATCH)            // 32 (dir,batch)
#define GM_F32  (2 * DB * NPTS)        // 262144 f32 = 1 MB

static __device__ __forceinline__ unsigned bf16rn(float f) {
  unsigned u = __float_as_uint(f);
  return (u + 0x7FFFu + ((u >> 16) & 1u)) >> 16;   // round-to-nearest-even
}
static __device__ __forceinline__ float bf2f(unsigned h) {
  return __uint_as_float(h << 16);
}
static __device__ __forceinline__ unsigned pk(unsigned lo, unsigned hi) {
  return (lo & 0xFFFFu) | (hi << 16);
}

static __device__ __forceinline__ float mintree16(const f32x16& a) {
  float m0 = fminf(fminf(a[0],  a[1]),  a[2]);     // v_min3 chains
  float m1 = fminf(fminf(a[3],  a[4]),  a[5]);
  float m2 = fminf(fminf(a[6],  a[7]),  a[8]);
  float m3 = fminf(fminf(a[9],  a[10]), a[11]);
  float m4 = fminf(fminf(a[12], a[13]), a[14]);
  float m5 = fminf(fminf(a[15], m0), m1);
  float m6 = fminf(fminf(m2, m3), m4);
  return fminf(m5, m6);
}

__global__ __launch_bounds__(512, 2) void chamfer_mm(
    const float* __restrict__ x, const float* __restrict__ y,
    float* __restrict__ gm, unsigned* __restrict__ cnt) {
  // 64 m-tiles x 64 uint4 (tile layout: [kh(2)][row(32)]) = 64 KB
  __shared__ __align__(16) uint4 afl[64 * 64];

  const int bid = blockIdx.x;          // 512 = 32 db x 8 own-chunks x 2 halves
  const int tid = threadIdx.x;
  if (bid == 0 && tid == 0) *cnt = 0;  // combine's counter (stream-ordered)

  const int db  = bid >> 4;
  const int r   = bid & 15;
  const int c   = r >> 1;              // own chunk [0,8)
  const int h   = r & 1;               // m-half
  const int dir = db >> 4, b = db & 15;
  const float* own   = (dir == 0 ? x : y) + (size_t)b * NPTS * 3;
  const float* other = (dir == 0 ? y : x) + (size_t)b * NPTS * 3;
  const float* mp    = other + (size_t)h * 2048 * 3;

  // ---- stage: convert 2048 other pts -> A-frags in LDS (4 pts/thread) ----
  #pragma unroll
  for (int k = 0; k < 4; ++k) {
    const int p = tid + k * 512;       // [0,2048)
    float y0 = mp[p * 3 + 0], y1 = mp[p * 3 + 1], y2 = mp[p * 3 + 2];
    float wv = fmaf(y2, y2, fmaf(y1, y1, y0 * y0));
    float z0 = -2.f * y0, z1 = -2.f * y1, z2 = -2.f * y2;
    unsigned h0 = bf16rn(z0), h1 = bf16rn(z1), h2 = bf16rn(z2);
    unsigned e0 = bf16rn(z0 - bf2f(h0));
    unsigned e1 = bf16rn(z1 - bf2f(h1));
    unsigned e2 = bf16rn(z2 - bf2f(h2));
    unsigned wh = bf16rn(wv), wl = bf16rn(wv - bf2f(wh));
    const int tile = p >> 5, row = p & 31;
    afl[tile * 64 + row]      =
        make_uint4(pk(h0, h1), pk(h2, e0), pk(e1, e2), pk(h0, h1)); // K0-7
    afl[tile * 64 + 32 + row] =
        make_uint4(pk(h2, wh), pk(wl, 0u), 0u, 0u);                 // K8-15
  }

  // ---- resident B-frags: 64 own pts per wave (2 n-tiles of 32) ----------
  const int w = tid >> 6, l = tid & 63;
  const int col = l & 31, kh = l >> 5;
  const unsigned ONE = 0x3F80u;
  bf16x8 bfr[2];
  float sq[2], rmn[2];
  #pragma unroll
  for (int nt = 0; nt < 2; ++nt) {
    const int n = c * 512 + w * 64 + nt * 32 + col;
    float a0 = own[n * 3 + 0], a1 = own[n * 3 + 1], a2 = own[n * 3 + 2];
    sq[nt]  = fmaf(a2, a2, fmaf(a1, a1, a0 * a0));   // exact f32, added last
    rmn[nt] = 1e30f;
    unsigned h0 = bf16rn(a0), h1 = bf16rn(a1), h2 = bf16rn(a2);
    unsigned e0 = bf16rn(a0 - bf2f(h0));
    unsigned e1 = bf16rn(a1 - bf2f(h1));
    unsigned e2 = bf16rn(a2 - bf2f(h2));
    union { unsigned uu[4]; bf16x8 v; } U;
    U.uu[0] = (kh == 0) ? pk(h0, h1) : pk(e2, ONE);
    U.uu[1] = (kh == 0) ? pk(h2, h0) : pk(ONE, 0u);
    U.uu[2] = (kh == 0) ? pk(h1, h2) : 0u;
    U.uu[3] = (kh == 0) ? pk(e0, e1) : 0u;
    bfr[nt] = U.v;
  }
  __syncthreads();

  // ---- main loop: ACC-pipelined (issue mt+1 before reading mt) ----------
  const int aoff = kh * 32 + col;      // lane's uint4 index within a tile
  const f32x16 z16 = {0.f, 0.f, 0.f, 0.f, 0.f, 0.f, 0.f, 0.f,
                      0.f, 0.f, 0.f, 0.f, 0.f, 0.f, 0.f, 0.f};
  union { uint4 u; bf16x8 v; } A;
  A.u = afl[aoff];                     // tile 0
  f32x16 accP0 = __builtin_amdgcn_mfma_f32_32x32x16_bf16(A.v, bfr[0], z16,
                                                         0, 0, 0);
  f32x16 accP1 = __builtin_amdgcn_mfma_f32_32x32x16_bf16(A.v, bfr[1], z16,
                                                         0, 0, 0);
  #pragma unroll 2
  for (int mt = 1; mt < 64; ++mt) {
    A.u = afl[mt * 64 + aoff];
    // issue next tile's MFMAs first: they drain while we read the previous
    f32x16 accC0 = __builtin_amdgcn_mfma_f32_32x32x16_bf16(A.v, bfr[0], z16,
                                                           0, 0, 0);
    f32x16 accC1 = __builtin_amdgcn_mfma_f32_32x32x16_bf16(A.v, bfr[1], z16,
                                                           0, 0, 0);
    rmn[0] = fminf(rmn[0], mintree16(accP0));        // reads tile mt-1
    rmn[1] = fminf(rmn[1], mintree16(accP1));
    accP0 = accC0;                                   // rotation (unroll 2)
    accP1 = accC1;
  }
  rmn[0] = fminf(rmn[0], mintree16(accP0));          // drain tile 63
  rmn[1] = fminf(rmn[1], mintree16(accP1));

  // ---- epilogue: rows live in both lane halves -> fold lane^32 ----------
  #pragma unroll
  for (int nt = 0; nt < 2; ++nt) {
    float v = fminf(rmn[nt], __shfl_xor(rmn[nt], 32, 64));
    float sv = v + sq[nt];
    if (l < 32)
      gm[(size_t)(h * DB + db) * NPTS + c * 512 + w * 64 + nt * 32 + col] = sv;
  }
}

// 32 blocks: min over halves + per-db mean; last block folds max/mean -> out.
__global__ __launch_bounds__(256) void chamfer_combine(
    const float* __restrict__ gm, float* __restrict__ dist,
    unsigned* __restrict__ cnt, float* __restrict__ out) {
  const int db = blockIdx.x;
  const float* g0 = gm + (size_t)db * NPTS;
  const float* g1 = gm + (size_t)(DB + db) * NPTS;
  float s = 0.0f;
  for (int i = threadIdx.x; i < NPTS; i += 256)
    s += fminf(g0[i], g1[i]);
  #pragma unroll
  for (int off = 32; off > 0; off >>= 1) s += __shfl_down(s, off, 64);
  __shared__ float red[4];
  const int lane = threadIdx.x & 63, wid = threadIdx.x >> 6;
  if (lane == 0) red[wid] = s;
  __syncthreads();
  if (threadIdx.x == 0) {
    dist[db] = ((red[0] + red[1]) + (red[2] + red[3])) * (1.0f / (float)NPTS);
    __threadfence();
    unsigned old = __hip_atomic_fetch_add(cnt, 1u, __ATOMIC_ACQ_REL,
                                          __HIP_MEMORY_SCOPE_AGENT);
    if (old == DB - 1) {
      __threadfence();
      float acc = 0.0f;
      #pragma unroll
      for (int b = 0; b < BATCH; ++b) {
        float d0 = __uint_as_float(__hip_atomic_load(
            (const unsigned*)&dist[b], __ATOMIC_RELAXED,
            __HIP_MEMORY_SCOPE_AGENT));
        float d1 = __uint_as_float(__hip_atomic_load(
            (const unsigned*)&dist[b + BATCH], __ATOMIC_RELAXED,
            __HIP_MEMORY_SCOPE_AGENT));
        acc += fmaxf(d0, d1);
      }
      out[0] = acc * (1.0f / (float)BATCH);
    }
  }
}

extern "C" void kernel_launch(void* const* d_in, const int* in_sizes, int n_in,
                              void* d_out, int out_size, void* d_ws, size_t ws_size,
                              hipStream_t stream) {
  const float* x = (const float*)d_in[0];
  const float* y = (const float*)d_in[1];
  float* out = (float*)d_out;

  float* gm     = (float*)d_ws;                    // 1 MB
  float* dist   = gm + GM_F32;                     // 32 f32
  unsigned* cnt = (unsigned*)(dist + DB);          // 1 u32

  chamfer_mm<<<512, 512, 0, stream>>>(x, y, gm, cnt);
  chamfer_combine<<<DB, 256, 0, stream>>>(gm, dist, cnt, out);
}

// Round 20
// 29.554 us; speedup vs baseline: 18.1817x; 14.6466x over previous
//
#include <hip/hip_runtime.h>

// MaxChamferDistance: x[16,4096,3], y[16,4096,3] f32 -> scalar f32
//
// Round-20: r18/r19's acc-pipeline tests both corrupted by wide-vector
// rotation spill (1.5-1.9GB scratch) -- mechanism untestable in HIP.
// Clean remaining hypothesis: r12 reports VGPR_Count=64 => compiler is
// occupancy-greedy (8 waves/EU VGPR target; LDS caps at 4 anyway) and parks
// MFMA accs in AGPRs; per-element VALU reads of AGPR-resident accs would
// explain the ~112 vs ~50 cy/MFMA gap. ONE change vs the r12 champion
// (29.8us, absmax 0 x8): __launch_bounds__(512,4) -> (512) so the allocator
// may use up to 256 VGPRs and keep acc in arch VGPRs. Plain loop, no
// rotation (never spilled). Discriminator: VGPR_Count>100 + FETCH ~6MB.

typedef __attribute__((ext_vector_type(8)))  short bf16x8;
typedef __attribute__((ext_vector_type(16))) float f32x16;

#define BATCH   16
#define NPTS    4096
#define DB      (2 * BATCH)            // 32 (dir,batch)
#define GM_F32  (2 * DB * NPTS)        // 262144 f32 = 1 MB

static __device__ __forceinline__ unsigned bf16rn(float f) {
  unsigned u = __float_as_uint(f);
  return (u + 0x7FFFu + ((u >> 16) & 1u)) >> 16;   // round-to-nearest-even
}
static __device__ __forceinline__ float bf2f(unsigned h) {
  return __uint_as_float(h << 16);
}
static __device__ __forceinline__ unsigned pk(unsigned lo, unsigned hi) {
  return (lo & 0xFFFFu) | (hi << 16);
}

__global__ __launch_bounds__(512) void chamfer_mm(
    const float* __restrict__ x, const float* __restrict__ y,
    float* __restrict__ gm, unsigned* __restrict__ cnt) {
  // 64 m-tiles x 64 uint4 (tile layout: [kh(2)][row(32)]) = 64 KB
  __shared__ __align__(16) uint4 afl[64 * 64];

  const int bid = blockIdx.x;          // 512 = 32 db x 8 own-chunks x 2 halves
  const int tid = threadIdx.x;
  if (bid == 0 && tid == 0) *cnt = 0;  // combine's counter (stream-ordered)

  const int db  = bid >> 4;
  const int r   = bid & 15;
  const int c   = r >> 1;              // own chunk [0,8)
  const int h   = r & 1;               // m-half
  const int dir = db >> 4, b = db & 15;
  const float* own   = (dir == 0 ? x : y) + (size_t)b * NPTS * 3;
  const float* other = (dir == 0 ? y : x) + (size_t)b * NPTS * 3;
  const float* mp    = other + (size_t)h * 2048 * 3;

  // ---- stage: convert 2048 other pts -> A-frags in LDS (4 pts/thread) ----
  #pragma unroll
  for (int k = 0; k < 4; ++k) {
    const int p = tid + k * 512;       // [0,2048)
    float y0 = mp[p * 3 + 0], y1 = mp[p * 3 + 1], y2 = mp[p * 3 + 2];
    float wv = fmaf(y2, y2, fmaf(y1, y1, y0 * y0));
    float z0 = -2.f * y0, z1 = -2.f * y1, z2 = -2.f * y2;
    unsigned h0 = bf16rn(z0), h1 = bf16rn(z1), h2 = bf16rn(z2);
    unsigned e0 = bf16rn(z0 - bf2f(h0));
    unsigned e1 = bf16rn(z1 - bf2f(h1));
    unsigned e2 = bf16rn(z2 - bf2f(h2));
    unsigned wh = bf16rn(wv), wl = bf16rn(wv - bf2f(wh));
    const int tile = p >> 5, row = p & 31;
    afl[tile * 64 + row]      =
        make_uint4(pk(h0, h1), pk(h2, e0), pk(e1, e2), pk(h0, h1)); // K0-7
    afl[tile * 64 + 32 + row] =
        make_uint4(pk(h2, wh), pk(wl, 0u), 0u, 0u);                 // K8-15
  }

  // ---- resident B-frags: 64 own pts per wave (2 n-tiles of 32) ----------
  const int w = tid >> 6, l = tid & 63;
  const int col = l & 31, kh = l >> 5;
  const unsigned ONE = 0x3F80u;
  bf16x8 bfr[2];
  float sq[2], rmn[2];
  #pragma unroll
  for (int nt = 0; nt < 2; ++nt) {
    const int n = c * 512 + w * 64 + nt * 32 + col;
    float a0 = own[n * 3 + 0], a1 = own[n * 3 + 1], a2 = own[n * 3 + 2];
    sq[nt]  = fmaf(a2, a2, fmaf(a1, a1, a0 * a0));   // exact f32, added last
    rmn[nt] = 1e30f;
    unsigned h0 = bf16rn(a0), h1 = bf16rn(a1), h2 = bf16rn(a2);
    unsigned e0 = bf16rn(a0 - bf2f(h0));
    unsigned e1 = bf16rn(a1 - bf2f(h1));
    unsigned e2 = bf16rn(a2 - bf2f(h2));
    union { unsigned uu[4]; bf16x8 v; } U;
    U.uu[0] = (kh == 0) ? pk(h0, h1) : pk(e2, ONE);
    U.uu[1] = (kh == 0) ? pk(h2, h0) : pk(ONE, 0u);
    U.uu[2] = (kh == 0) ? pk(h1, h2) : 0u;
    U.uu[3] = (kh == 0) ? pk(e0, e1) : 0u;
    bfr[nt] = U.v;
  }
  __syncthreads();

  // ---- main loop: 64 tiles x [1 ds_read_b128 + 2 MFMA + min3 tree] ------
  const int aoff = kh * 32 + col;      // lane's uint4 index within a tile
  const f32x16 z16 = {0.f, 0.f, 0.f, 0.f, 0.f, 0.f, 0.f, 0.f,
                      0.f, 0.f, 0.f, 0.f, 0.f, 0.f, 0.f, 0.f};
  #pragma unroll 4
  for (int mt = 0; mt < 64; ++mt) {
    union { uint4 u; bf16x8 v; } A;
    A.u = afl[mt * 64 + aoff];
    #pragma unroll
    for (int nt = 0; nt < 2; ++nt) {
      f32x16 acc = __builtin_amdgcn_mfma_f32_32x32x16_bf16(
          A.v, bfr[nt], z16, 0, 0, 0);
      float m0 = fminf(fminf(acc[0],  acc[1]),  acc[2]);   // v_min3 chains
      float m1 = fminf(fminf(acc[3],  acc[4]),  acc[5]);
      float m2 = fminf(fminf(acc[6],  acc[7]),  acc[8]);
      float m3 = fminf(fminf(acc[9],  acc[10]), acc[11]);
      float m4 = fminf(fminf(acc[12], acc[13]), acc[14]);
      float m5 = fminf(fminf(acc[15], m0), m1);
      float m6 = fminf(fminf(m2, m3), m4);
      rmn[nt] = fminf(fminf(m5, m6), rmn[nt]);
    }
  }

  // ---- epilogue: rows live in both lane halves -> fold lane^32 ----------
  #pragma unroll
  for (int nt = 0; nt < 2; ++nt) {
    float v = fminf(rmn[nt], __shfl_xor(rmn[nt], 32, 64));
    float sv = v + sq[nt];
    if (l < 32)
      gm[(size_t)(h * DB + db) * NPTS + c * 512 + w * 64 + nt * 32 + col] = sv;
  }
}

// 32 blocks: min over halves + per-db mean; last block folds max/mean -> out.
__global__ __launch_bounds__(256) void chamfer_combine(
    const float* __restrict__ gm, float* __restrict__ dist,
    unsigned* __restrict__ cnt, float* __restrict__ out) {
  const int db = blockIdx.x;
  const float* g0 = gm + (size_t)db * NPTS;
  const float* g1 = gm + (size_t)(DB + db) * NPTS;
  float s = 0.0f;
  for (int i = threadIdx.x; i < NPTS; i += 256)
    s += fminf(g0[i], g1[i]);
  #pragma unroll
  for (int off = 32; off > 0; off >>= 1) s += __shfl_down(s, off, 64);
  __shared__ float red[4];
  const int lane = threadIdx.x & 63, wid = threadIdx.x >> 6;
  if (lane == 0) red[wid] = s;
  __syncthreads();
  if (threadIdx.x == 0) {
    dist[db] = ((red[0] + red[1]) + (red[2] + red[3])) * (1.0f / (float)NPTS);
    __threadfence();
    unsigned old = __hip_atomic_fetch_add(cnt, 1u, __ATOMIC_ACQ_REL,
                                          __HIP_MEMORY_SCOPE_AGENT);
    if (old == DB - 1) {
      __threadfence();
      float acc = 0.0f;
      #pragma unroll
      for (int b = 0; b < BATCH; ++b) {
        float d0 = __uint_as_float(__hip_atomic_load(
            (const unsigned*)&dist[b], __ATOMIC_RELAXED,
            __HIP_MEMORY_SCOPE_AGENT));
        float d1 = __uint_as_float(__hip_atomic_load(
            (const unsigned*)&dist[b + BATCH], __ATOMIC_RELAXED,
            __HIP_MEMORY_SCOPE_AGENT));
        acc += fmaxf(d0, d1);
      }
      out[0] = acc * (1.0f / (float)BATCH);
    }
  }
}

extern "C" void kernel_launch(void* const* d_in, const int* in_sizes, int n_in,
                              void* d_out, int out_size, void* d_ws, size_t ws_size,
                              hipStream_t stream) {
  const float* x = (const float*)d_in[0];
  const float* y = (const float*)d_in[1];
  float* out = (float*)d_out;

  float* gm     = (float*)d_ws;                    // 1 MB
  float* dist   = gm + GM_F32;                     // 32 f32
  unsigned* cnt = (unsigned*)(dist + DB);          // 1 u32

  chamfer_mm<<<512, 512, 0, stream>>>(x, y, gm, cnt);
  chamfer_combine<<<DB, 256, 0, stream>>>(gm, dist, cnt, out);
}